// Round 3
// baseline (148.041 us; speedup 1.0000x reference)
//
#include <hip/hip_runtime.h>
#include <hip/hip_bf16.h>
#include <stdint.h>

#define N_NODES 8192
#define WORDS_PER_ROW 256   // 8192 / 32
#define NWORDS (N_NODES * WORDS_PER_ROW)
#define H_DIM 64
#define NG 128              // NUM_GRAPHS
#define MAXD 128            // max degree capacity (mean 32, Poisson tail-safe)

// workspace byte offsets
#define OFF_BITMAP 0u
#define OFF_NNZ    (8u * 1024 * 1024)
#define OFF_POOLED (OFF_NNZ + 32u * 1024)
#define OFF_CNT    (OFF_POOLED + 32u * 1024)
#define ZERO_BYTES (OFF_CNT + 512u)
#define OFF_COLS   ZERO_BYTES
#define OFF_BUFA   (OFF_COLS + 2u * 1024 * 1024)
#define OFF_BUFB   (OFF_BUFA + 2u * 1024 * 1024)

__device__ __forceinline__ float bc(float v, int k) {  // wave broadcast lane k
    return __int_as_float(__builtin_amdgcn_readlane(__float_as_int(v), k));
}

// ---- set adjacency bits: A[r,c] = 1 (set semantics via OR) ----
__global__ void edge_bits_kernel(const int* __restrict__ ei, int E,
                                 unsigned int* __restrict__ bitmap) {
    int k = blockIdx.x * blockDim.x + threadIdx.x;
    if (k >= E) return;
    int r = ei[k];
    int c = ei[E + k];
    atomicOr(&bitmap[(r << 8) + (c >> 5)], 1u << (c & 31));
}

// ---- parallel CSR: one thread per bitmap word, unordered within row ----
__global__ void csr_par_kernel(const unsigned int* __restrict__ bitmap,
                               int* __restrict__ nnz,
                               unsigned short* __restrict__ cols) {
    int idx = blockIdx.x * blockDim.x + threadIdx.x;   // word index
    unsigned int w = bitmap[idx];
    if (!w) return;
    int row = idx >> 8;
    int pos = atomicAdd(&nnz[row], __popc(w));
    unsigned short* crow = cols + row * MAXD;
    int base = (idx & 255) << 5;
    while (w) {
        int b = __ffs(w) - 1; w &= w - 1;
        crow[pos++] = (unsigned short)(base + b);
    }
}

// ---- layer-1 dense: ht[i,f] = dinv_i * sum_k x[i,k] * th1[k,f]   (K=7) ----
__global__ void mm1_kernel(const float* __restrict__ x, const float* __restrict__ th,
                           const int* __restrict__ nnz, float* __restrict__ out) {
    __shared__ float sT[7 * 64];
    __shared__ float sX[4 * 7];
    int row0 = blockIdx.x << 2;
    for (int t = threadIdx.x; t < 7 * 64; t += 256) sT[t] = th[t];
    if (threadIdx.x < 28) sX[threadIdx.x] = x[row0 * 7 + threadIdx.x];
    __syncthreads();
    int r = threadIdx.x >> 6, f = threadIdx.x & 63;
    float acc = 0.f;
    #pragma unroll
    for (int k = 0; k < 7; ++k) acc = fmaf(sX[r * 7 + k], sT[(k << 6) + f], acc);
    int row = row0 + r;
    float dinv = 1.0f / sqrtf((float)nnz[row] + 1.0f);
    out[(row << 6) + f] = acc * dinv;
}

// ---- fused SpMM + relu + dense theta: one wave per row ----
// h[i,:]  = relu( dinv_i * ( ht[i,:] + sum_j ht[j,:] ) )      (ht prescaled by dinv_j)
// out[i,f] = dinv_i * sum_k h[i,k] * th[k,f]
__global__ void spmm_theta_kernel(const unsigned short* __restrict__ cols,
                                  const int* __restrict__ nnz,
                                  const float* __restrict__ ht,
                                  const float* __restrict__ th,
                                  float* __restrict__ out) {
    __shared__ float sT[64 * 64];
    #pragma unroll
    for (int t = 0; t < 16; ++t) sT[threadIdx.x + (t << 8)] = th[threadIdx.x + (t << 8)];
    __syncthreads();

    int row  = (blockIdx.x << 2) + (threadIdx.x >> 6);
    int lane = threadIdx.x & 63;
    int n = nnz[row];
    float dinv = 1.0f / sqrtf((float)n + 1.0f);
    const unsigned short* crow = cols + row * MAXD;
    int j0 = crow[lane];
    int j1 = crow[64 + lane];
    float acc = ht[(row << 6) + lane];              // eye term
    int n0 = n < 64 ? n : 64;
    for (int t = 0; t < n0; ++t) {
        int j = __builtin_amdgcn_readlane(j0, t);   // SGPR neighbor id
        acc += ht[(j << 6) + lane];                 // s-base + lane offset, L2-hit
    }
    for (int t = 64; t < n; ++t) {
        int j = __builtin_amdgcn_readlane(j1, t - 64);
        acc += ht[(j << 6) + lane];
    }
    float h = fmaxf(acc * dinv, 0.f);               // relu'd hidden value, feature=lane
    float acc2 = 0.f;
    #pragma unroll
    for (int k = 0; k < 64; ++k)
        acc2 = fmaf(bc(h, k), sT[(k << 6) + lane], acc2);
    out[(row << 6) + lane] = acc2 * dinv;
}

// ---- last SpMM (no relu) + mean-pool accumulate ----
__global__ void spmm_pool_kernel(const unsigned short* __restrict__ cols,
                                 const int* __restrict__ nnz,
                                 const float* __restrict__ ht,
                                 const int* __restrict__ batch,
                                 float* __restrict__ pooled, int* __restrict__ cnt) {
    int row  = (blockIdx.x << 2) + (threadIdx.x >> 6);
    int lane = threadIdx.x & 63;
    int n = nnz[row];
    float dinv = 1.0f / sqrtf((float)n + 1.0f);
    const unsigned short* crow = cols + row * MAXD;
    int j0 = crow[lane];
    int j1 = crow[64 + lane];
    float acc = ht[(row << 6) + lane];
    int n0 = n < 64 ? n : 64;
    for (int t = 0; t < n0; ++t) {
        int j = __builtin_amdgcn_readlane(j0, t);
        acc += ht[(j << 6) + lane];
    }
    for (int t = 64; t < n; ++t) {
        int j = __builtin_amdgcn_readlane(j1, t - 64);
        acc += ht[(j << 6) + lane];
    }
    float res = acc * dinv;
    int g = batch[row];
    atomicAdd(&pooled[(g << 6) + lane], res);
    if (lane == 0) atomicAdd(&cnt[g], 1);
}

// ---- out[g,c] = b[c] + sum_f relu(pooled[g,f]/cnt[g]) * W[f,c] ----
__global__ void final_kernel(const float* __restrict__ pooled, const int* __restrict__ cnt,
                             const float* __restrict__ W, const float* __restrict__ b,
                             float* __restrict__ out) {
    int g = threadIdx.x >> 1;
    int c = threadIdx.x & 1;
    int n = cnt[g]; if (n < 1) n = 1;
    float inv = 1.0f / (float)n;
    float acc = b[c];
    #pragma unroll
    for (int f = 0; f < 64; ++f) {
        float p = fmaxf(pooled[(g << 6) + f] * inv, 0.f);
        acc = fmaf(p, W[(f << 1) + c], acc);
    }
    out[(g << 1) + c] = acc;
}

extern "C" void kernel_launch(void* const* d_in, const int* in_sizes, int n_in,
                              void* d_out, int out_size, void* d_ws, size_t ws_size,
                              hipStream_t stream) {
    const float* x     = (const float*)d_in[0];
    const int*   ei    = (const int*)d_in[1];
    const int*   batch = (const int*)d_in[2];
    const float* th1   = (const float*)d_in[3];
    const float* th2   = (const float*)d_in[4];
    const float* th3   = (const float*)d_in[5];
    const float* W     = (const float*)d_in[6];
    const float* b     = (const float*)d_in[7];
    float* out = (float*)d_out;
    int E = in_sizes[1] / 2;

    char* ws = (char*)d_ws;
    unsigned int*   bitmap = (unsigned int*)(ws + OFF_BITMAP);
    int*            nnz    = (int*)(ws + OFF_NNZ);
    float*          pooled = (float*)(ws + OFF_POOLED);
    int*            cnt    = (int*)(ws + OFF_CNT);
    unsigned short* cols   = (unsigned short*)(ws + OFF_COLS);
    float*          bufA   = (float*)(ws + OFF_BUFA);
    float*          bufB   = (float*)(ws + OFF_BUFB);

    hipMemsetAsync(ws, 0, ZERO_BYTES, stream);   // bitmap + nnz + pooled + cnt

    edge_bits_kernel<<<(E + 255) / 256, 256, 0, stream>>>(ei, E, bitmap);
    csr_par_kernel<<<NWORDS / 256, 256, 0, stream>>>(bitmap, nnz, cols);

    mm1_kernel<<<N_NODES / 4, 256, 0, stream>>>(x, th1, nnz, bufA);
    spmm_theta_kernel<<<N_NODES / 4, 256, 0, stream>>>(cols, nnz, bufA, th2, bufB);
    spmm_theta_kernel<<<N_NODES / 4, 256, 0, stream>>>(cols, nnz, bufB, th3, bufA);
    spmm_pool_kernel<<<N_NODES / 4, 256, 0, stream>>>(cols, nnz, bufA, batch, pooled, cnt);
    final_kernel<<<1, 256, 0, stream>>>(pooled, cnt, W, b, out);
}

// Round 4
// 109.222 us; speedup vs baseline: 1.3554x; 1.3554x over previous
//
#include <hip/hip_runtime.h>
#include <hip/hip_bf16.h>
#include <stdint.h>

#define N_NODES 8192
#define WORDS_PER_ROW 256   // 8192 / 32
#define H_DIM 64
#define NG 128              // NUM_GRAPHS
#define MAXD 128            // max degree capacity (Binomial(262144, 1/8192), mean 32 — 128 is tail-safe)

// workspace byte offsets
#define OFF_BITMAP 0u
#define OFF_NNZ    (8u * 1024 * 1024)
#define OFF_POOLED (OFF_NNZ + 32u * 1024)
#define OFF_CNT    (OFF_POOLED + 32u * 1024)
#define ZERO_BYTES (OFF_CNT + 512u)
#define OFF_COLS   ZERO_BYTES
#define OFF_BUFA   (OFF_COLS + 2u * 1024 * 1024)
#define OFF_BUFB   (OFF_BUFA + 2u * 1024 * 1024)

__device__ __forceinline__ float bc(float v, int k) {  // wave broadcast lane k
    return __int_as_float(__builtin_amdgcn_readlane(__float_as_int(v), k));
}

// ---- fused dedup + CSR: atomicOr claims the bit; winner appends column ----
// A[r,c] = 1 with set semantics (duplicates collapse: only the first setter appends).
__global__ void edge_csr_kernel(const int* __restrict__ ei, int E,
                                unsigned int* __restrict__ bitmap,
                                int* __restrict__ nnz,
                                unsigned short* __restrict__ cols) {
    int k = blockIdx.x * blockDim.x + threadIdx.x;
    if (k >= E) return;
    int r = ei[k];
    int c = ei[E + k];
    unsigned int bit = 1u << (c & 31);
    unsigned int old = atomicOr(&bitmap[(r << 8) + (c >> 5)], bit);
    if (!(old & bit)) {                      // first time this (r,c) appears
        int pos = atomicAdd(&nnz[r], 1);
        cols[r * MAXD + pos] = (unsigned short)c;
    }
}

// ---- layer-1 dense: ht[i,f] = dinv_i * sum_k x[i,k] * th1[k,f]   (K=7) ----
__global__ void mm1_kernel(const float* __restrict__ x, const float* __restrict__ th,
                           const int* __restrict__ nnz, float* __restrict__ out) {
    __shared__ float sT[7 * 64];
    __shared__ float sX[4 * 7];
    int row0 = blockIdx.x << 2;
    for (int t = threadIdx.x; t < 7 * 64; t += 256) sT[t] = th[t];
    if (threadIdx.x < 28) sX[threadIdx.x] = x[row0 * 7 + threadIdx.x];
    __syncthreads();
    int r = threadIdx.x >> 6, f = threadIdx.x & 63;
    float acc = 0.f;
    #pragma unroll
    for (int k = 0; k < 7; ++k) acc = fmaf(sX[r * 7 + k], sT[(k << 6) + f], acc);
    int row = row0 + r;
    float dinv = 1.0f / sqrtf((float)nnz[row] + 1.0f);
    out[(row << 6) + f] = acc * dinv;
}

// ---- fused SpMM + relu + dense theta: one wave per row ----
// h[i,:]  = relu( dinv_i * ( ht[i,:] + sum_j ht[j,:] ) )      (ht prescaled by dinv_j)
// out[i,f] = dinv_i * sum_k h[i,k] * th[k,f]
__global__ void spmm_theta_kernel(const unsigned short* __restrict__ cols,
                                  const int* __restrict__ nnz,
                                  const float* __restrict__ ht,
                                  const float* __restrict__ th,
                                  float* __restrict__ out) {
    __shared__ float sT[64 * 64];
    #pragma unroll
    for (int t = 0; t < 16; ++t) sT[threadIdx.x + (t << 8)] = th[threadIdx.x + (t << 8)];
    __syncthreads();

    int row  = (blockIdx.x << 2) + (threadIdx.x >> 6);
    int lane = threadIdx.x & 63;
    int n = nnz[row];
    float dinv = 1.0f / sqrtf((float)n + 1.0f);
    const unsigned short* crow = cols + row * MAXD;
    int j0 = crow[lane];
    int j1 = crow[64 + lane];
    float acc = ht[(row << 6) + lane];              // eye term
    int n0 = n < 64 ? n : 64;
    for (int t = 0; t < n0; ++t) {
        int j = __builtin_amdgcn_readlane(j0, t);   // SGPR neighbor id
        acc += ht[(j << 6) + lane];                 // 256B coalesced row gather, L2-hit
    }
    for (int t = 64; t < n; ++t) {
        int j = __builtin_amdgcn_readlane(j1, t - 64);
        acc += ht[(j << 6) + lane];
    }
    float h = fmaxf(acc * dinv, 0.f);               // relu'd hidden value, feature=lane
    float acc2 = 0.f;
    #pragma unroll
    for (int k = 0; k < 64; ++k)
        acc2 = fmaf(bc(h, k), sT[(k << 6) + lane], acc2);
    out[(row << 6) + lane] = acc2 * dinv;
}

// ---- last SpMM (no relu) + mean-pool accumulate ----
__global__ void spmm_pool_kernel(const unsigned short* __restrict__ cols,
                                 const int* __restrict__ nnz,
                                 const float* __restrict__ ht,
                                 const int* __restrict__ batch,
                                 float* __restrict__ pooled, int* __restrict__ cnt) {
    int row  = (blockIdx.x << 2) + (threadIdx.x >> 6);
    int lane = threadIdx.x & 63;
    int n = nnz[row];
    float dinv = 1.0f / sqrtf((float)n + 1.0f);
    const unsigned short* crow = cols + row * MAXD;
    int j0 = crow[lane];
    int j1 = crow[64 + lane];
    float acc = ht[(row << 6) + lane];
    int n0 = n < 64 ? n : 64;
    for (int t = 0; t < n0; ++t) {
        int j = __builtin_amdgcn_readlane(j0, t);
        acc += ht[(j << 6) + lane];
    }
    for (int t = 64; t < n; ++t) {
        int j = __builtin_amdgcn_readlane(j1, t - 64);
        acc += ht[(j << 6) + lane];
    }
    float res = acc * dinv;
    int g = batch[row];
    atomicAdd(&pooled[(g << 6) + lane], res);
    if (lane == 0) atomicAdd(&cnt[g], 1);
}

// ---- out[g,c] = b[c] + sum_f relu(pooled[g,f]/cnt[g]) * W[f,c] ----
__global__ void final_kernel(const float* __restrict__ pooled, const int* __restrict__ cnt,
                             const float* __restrict__ W, const float* __restrict__ b,
                             float* __restrict__ out) {
    int g = threadIdx.x >> 1;
    int c = threadIdx.x & 1;
    int n = cnt[g]; if (n < 1) n = 1;
    float inv = 1.0f / (float)n;
    float acc = b[c];
    #pragma unroll
    for (int f = 0; f < 64; ++f) {
        float p = fmaxf(pooled[(g << 6) + f] * inv, 0.f);
        acc = fmaf(p, W[(f << 1) + c], acc);
    }
    out[(g << 1) + c] = acc;
}

extern "C" void kernel_launch(void* const* d_in, const int* in_sizes, int n_in,
                              void* d_out, int out_size, void* d_ws, size_t ws_size,
                              hipStream_t stream) {
    const float* x     = (const float*)d_in[0];
    const int*   ei    = (const int*)d_in[1];
    const int*   batch = (const int*)d_in[2];
    const float* th1   = (const float*)d_in[3];
    const float* th2   = (const float*)d_in[4];
    const float* th3   = (const float*)d_in[5];
    const float* W     = (const float*)d_in[6];
    const float* b     = (const float*)d_in[7];
    float* out = (float*)d_out;
    int E = in_sizes[1] / 2;

    char* ws = (char*)d_ws;
    unsigned int*   bitmap = (unsigned int*)(ws + OFF_BITMAP);
    int*            nnz    = (int*)(ws + OFF_NNZ);
    float*          pooled = (float*)(ws + OFF_POOLED);
    int*            cnt    = (int*)(ws + OFF_CNT);
    unsigned short* cols   = (unsigned short*)(ws + OFF_COLS);
    float*          bufA   = (float*)(ws + OFF_BUFA);
    float*          bufB   = (float*)(ws + OFF_BUFB);

    hipMemsetAsync(ws, 0, ZERO_BYTES, stream);   // bitmap + nnz + pooled + cnt

    edge_csr_kernel<<<(E + 255) / 256, 256, 0, stream>>>(ei, E, bitmap, nnz, cols);

    mm1_kernel<<<N_NODES / 4, 256, 0, stream>>>(x, th1, nnz, bufA);
    spmm_theta_kernel<<<N_NODES / 4, 256, 0, stream>>>(cols, nnz, bufA, th2, bufB);
    spmm_theta_kernel<<<N_NODES / 4, 256, 0, stream>>>(cols, nnz, bufB, th3, bufA);
    spmm_pool_kernel<<<N_NODES / 4, 256, 0, stream>>>(cols, nnz, bufA, batch, pooled, cnt);
    final_kernel<<<1, 256, 0, stream>>>(pooled, cnt, W, b, out);
}

// Round 11
// 109.093 us; speedup vs baseline: 1.3570x; 1.0012x over previous
//
#include <hip/hip_runtime.h>
#include <hip/hip_bf16.h>
#include <stdint.h>

#define N_NODES 8192
#define WORDS_PER_ROW 256   // 8192 / 32
#define H_DIM 64
#define NG 128              // NUM_GRAPHS
#define MAXD 128            // max degree capacity (Binomial(262144, 1/8192), mean 32 — 128 is tail-safe)

// workspace byte offsets
#define OFF_BITMAP 0u
#define OFF_NNZ    (8u * 1024 * 1024)
#define OFF_POOLED (OFF_NNZ + 32u * 1024)
#define OFF_CNT    (OFF_POOLED + 32u * 1024)
#define ZERO_BYTES (OFF_CNT + 512u)
#define OFF_COLS   ZERO_BYTES
#define OFF_BUFA   (OFF_COLS + 2u * 1024 * 1024)
#define OFF_BUFB   (OFF_BUFA + 2u * 1024 * 1024)

__device__ __forceinline__ float bc(float v, int k) {  // wave broadcast lane k
    return __int_as_float(__builtin_amdgcn_readlane(__float_as_int(v), k));
}

// ---- fused dedup + CSR: atomicOr claims the bit; winner appends column ----
// A[r,c] = 1 with set semantics (duplicates collapse: only the first setter appends).
__global__ void edge_csr_kernel(const int* __restrict__ ei, int E,
                                unsigned int* __restrict__ bitmap,
                                int* __restrict__ nnz,
                                unsigned short* __restrict__ cols) {
    int k = blockIdx.x * blockDim.x + threadIdx.x;
    if (k >= E) return;
    int r = ei[k];
    int c = ei[E + k];
    unsigned int bit = 1u << (c & 31);
    unsigned int old = atomicOr(&bitmap[(r << 8) + (c >> 5)], bit);
    if (!(old & bit)) {                      // first time this (r,c) appears
        int pos = atomicAdd(&nnz[r], 1);
        cols[r * MAXD + pos] = (unsigned short)c;
    }
}

// ---- layer-1 dense: ht[i,f] = dinv_i * sum_k x[i,k] * th1[k,f]   (K=7) ----
__global__ void mm1_kernel(const float* __restrict__ x, const float* __restrict__ th,
                           const int* __restrict__ nnz, float* __restrict__ out) {
    __shared__ float sT[7 * 64];
    __shared__ float sX[4 * 7];
    int row0 = blockIdx.x << 2;
    for (int t = threadIdx.x; t < 7 * 64; t += 256) sT[t] = th[t];
    if (threadIdx.x < 28) sX[threadIdx.x] = x[row0 * 7 + threadIdx.x];
    __syncthreads();
    int r = threadIdx.x >> 6, f = threadIdx.x & 63;
    float acc = 0.f;
    #pragma unroll
    for (int k = 0; k < 7; ++k) acc = fmaf(sX[r * 7 + k], sT[(k << 6) + f], acc);
    int row = row0 + r;
    float dinv = 1.0f / sqrtf((float)nnz[row] + 1.0f);
    out[(row << 6) + f] = acc * dinv;
}

// ---- fused SpMM + relu + dense theta: one wave per row ----
// h[i,:]  = relu( dinv_i * ( ht[i,:] + sum_j ht[j,:] ) )      (ht prescaled by dinv_j)
// out[i,f] = dinv_i * sum_k h[i,k] * th[k,f]
__global__ void spmm_theta_kernel(const unsigned short* __restrict__ cols,
                                  const int* __restrict__ nnz,
                                  const float* __restrict__ ht,
                                  const float* __restrict__ th,
                                  float* __restrict__ out) {
    __shared__ float sT[64 * 64];
    #pragma unroll
    for (int t = 0; t < 16; ++t) sT[threadIdx.x + (t << 8)] = th[threadIdx.x + (t << 8)];
    __syncthreads();

    int row  = (blockIdx.x << 2) + (threadIdx.x >> 6);
    int lane = threadIdx.x & 63;
    int n = nnz[row];
    float dinv = 1.0f / sqrtf((float)n + 1.0f);
    const unsigned short* crow = cols + row * MAXD;
    int j0 = crow[lane];
    int j1 = crow[64 + lane];
    float acc = ht[(row << 6) + lane];              // eye term
    int n0 = n < 64 ? n : 64;
    for (int t = 0; t < n0; ++t) {
        int j = __builtin_amdgcn_readlane(j0, t);   // SGPR neighbor id
        acc += ht[(j << 6) + lane];                 // 256B coalesced row gather, L2-hit
    }
    for (int t = 64; t < n; ++t) {
        int j = __builtin_amdgcn_readlane(j1, t - 64);
        acc += ht[(j << 6) + lane];
    }
    float h = fmaxf(acc * dinv, 0.f);               // relu'd hidden value, feature=lane
    float acc2 = 0.f;
    #pragma unroll
    for (int k = 0; k < 64; ++k)
        acc2 = fmaf(bc(h, k), sT[(k << 6) + lane], acc2);
    out[(row << 6) + lane] = acc2 * dinv;
}

// ---- last SpMM (no relu) + mean-pool accumulate ----
__global__ void spmm_pool_kernel(const unsigned short* __restrict__ cols,
                                 const int* __restrict__ nnz,
                                 const float* __restrict__ ht,
                                 const int* __restrict__ batch,
                                 float* __restrict__ pooled, int* __restrict__ cnt) {
    int row  = (blockIdx.x << 2) + (threadIdx.x >> 6);
    int lane = threadIdx.x & 63;
    int n = nnz[row];
    float dinv = 1.0f / sqrtf((float)n + 1.0f);
    const unsigned short* crow = cols + row * MAXD;
    int j0 = crow[lane];
    int j1 = crow[64 + lane];
    float acc = ht[(row << 6) + lane];
    int n0 = n < 64 ? n : 64;
    for (int t = 0; t < n0; ++t) {
        int j = __builtin_amdgcn_readlane(j0, t);
        acc += ht[(j << 6) + lane];
    }
    for (int t = 64; t < n; ++t) {
        int j = __builtin_amdgcn_readlane(j1, t - 64);
        acc += ht[(j << 6) + lane];
    }
    float res = acc * dinv;
    int g = batch[row];
    atomicAdd(&pooled[(g << 6) + lane], res);
    if (lane == 0) atomicAdd(&cnt[g], 1);
}

// ---- out[g,c] = b[c] + sum_f relu(pooled[g,f]/cnt[g]) * W[f,c] ----
__global__ void final_kernel(const float* __restrict__ pooled, const int* __restrict__ cnt,
                             const float* __restrict__ W, const float* __restrict__ b,
                             float* __restrict__ out) {
    int g = threadIdx.x >> 1;
    int c = threadIdx.x & 1;
    int n = cnt[g]; if (n < 1) n = 1;
    float inv = 1.0f / (float)n;
    float acc = b[c];
    #pragma unroll
    for (int f = 0; f < 64; ++f) {
        float p = fmaxf(pooled[(g << 6) + f] * inv, 0.f);
        acc = fmaf(p, W[(f << 1) + c], acc);
    }
    out[(g << 1) + c] = acc;
}

extern "C" void kernel_launch(void* const* d_in, const int* in_sizes, int n_in,
                              void* d_out, int out_size, void* d_ws, size_t ws_size,
                              hipStream_t stream) {
    const float* x     = (const float*)d_in[0];
    const int*   ei    = (const int*)d_in[1];
    const int*   batch = (const int*)d_in[2];
    const float* th1   = (const float*)d_in[3];
    const float* th2   = (const float*)d_in[4];
    const float* th3   = (const float*)d_in[5];
    const float* W     = (const float*)d_in[6];
    const float* b     = (const float*)d_in[7];
    float* out = (float*)d_out;
    int E = in_sizes[1] / 2;

    char* ws = (char*)d_ws;
    unsigned int*   bitmap = (unsigned int*)(ws + OFF_BITMAP);
    int*            nnz    = (int*)(ws + OFF_NNZ);
    float*          pooled = (float*)(ws + OFF_POOLED);
    int*            cnt    = (int*)(ws + OFF_CNT);
    unsigned short* cols   = (unsigned short*)(ws + OFF_COLS);
    float*          bufA   = (float*)(ws + OFF_BUFA);
    float*          bufB   = (float*)(ws + OFF_BUFB);

    hipMemsetAsync(ws, 0, ZERO_BYTES, stream);   // bitmap + nnz + pooled + cnt

    edge_csr_kernel<<<(E + 255) / 256, 256, 0, stream>>>(ei, E, bitmap, nnz, cols);

    mm1_kernel<<<N_NODES / 4, 256, 0, stream>>>(x, th1, nnz, bufA);
    spmm_theta_kernel<<<N_NODES / 4, 256, 0, stream>>>(cols, nnz, bufA, th2, bufB);
    spmm_theta_kernel<<<N_NODES / 4, 256, 0, stream>>>(cols, nnz, bufB, th3, bufA);
    spmm_pool_kernel<<<N_NODES / 4, 256, 0, stream>>>(cols, nnz, bufA, batch, pooled, cnt);
    final_kernel<<<1, 256, 0, stream>>>(pooled, cnt, W, b, out);
}